// Round 6
// baseline (723.452 us; speedup 1.0000x reference)
//
#include <hip/hip_runtime.h>

#define HDIM 128
#define RDIM 64
#define NLAYERS 3

typedef unsigned int uint32;
typedef unsigned short ushort16;

// round-to-nearest-even fp32 -> bf16 (as raw ushort)
__device__ __forceinline__ ushort16 f2bf_rne(float x) {
  uint32 u = __float_as_uint(x);
  u += 0x7FFFu + ((u >> 16) & 1u);
  return (ushort16)(u >> 16);
}
__device__ __forceinline__ float bf_lo(uint32 p) { return __uint_as_float(p << 16); }
__device__ __forceinline__ float bf_hi(uint32 p) { return __uint_as_float(p & 0xFFFF0000u); }

// ---------------------------------------------------------------------------
// Phase 0: init degree counts (self-loop => 1) and out (= lin_b broadcast)
// ---------------------------------------------------------------------------
__global__ void k_prep(int* __restrict__ cnt, float* __restrict__ out,
                       const float* __restrict__ lin_b, int n) {
  int stride = gridDim.x * blockDim.x;
  int i0 = blockIdx.x * blockDim.x + threadIdx.x;
  for (int i = i0; i < n; i += stride) cnt[i] = 1;
  int total = n * RDIM;
  for (int i = i0; i < total; i += stride) out[i] = lin_b[i & (RDIM - 1)];
}

__global__ void k_count(const int* __restrict__ dst, int* __restrict__ cnt, int e) {
  int i = blockIdx.x * blockDim.x + threadIdx.x;
  if (i < e) atomicAdd(&cnt[dst[i]], 1);
}

// ---------------------------------------------------------------------------
// Two-level parallel exclusive scan over cnt[] -> rowptr/cursor (+ dis fused).
// ---------------------------------------------------------------------------
__global__ __launch_bounds__(1024) void k_scan1(const int* __restrict__ cnt,
                                                int* __restrict__ bsum, int n) {
  __shared__ int red[16];
  int tid = threadIdx.x;
  int gid = blockIdx.x * 1024 + tid;
  int v = (gid < n) ? cnt[gid] : 0;
#pragma unroll
  for (int off = 1; off < 64; off <<= 1) v += __shfl_xor(v, off);
  if ((tid & 63) == 0) red[tid >> 6] = v;
  __syncthreads();
  if (tid < 16) {
    int s = red[tid];
#pragma unroll
    for (int off = 1; off < 16; off <<= 1) s += __shfl_xor(s, off, 16);
    if (tid == 0) bsum[blockIdx.x] = s;
  }
}

__global__ __launch_bounds__(64) void k_scan2(const int* __restrict__ bsum,
                                              int* __restrict__ boff,
                                              int* __restrict__ rowptr,
                                              int nb, int n) {
  int lane = threadIdx.x;
  int carry = 0;
  for (int base = 0; base < nb; base += 64) {
    int i = base + lane;
    int v = (i < nb) ? bsum[i] : 0;
    int incl = v;
#pragma unroll
    for (int off = 1; off < 64; off <<= 1) {
      int t = __shfl_up(incl, off);
      if (lane >= off) incl += t;
    }
    if (i < nb) boff[i] = carry + incl - v;
    carry += __shfl(incl, 63);
  }
  if (lane == 0) rowptr[n] = carry;
}

__global__ __launch_bounds__(1024) void k_scan3(const int* __restrict__ cnt,
                                                const int* __restrict__ boff,
                                                int* __restrict__ rowptr,
                                                int* __restrict__ cursor,
                                                float* __restrict__ dis, int n) {
  __shared__ int wsum[16];
  int tid = threadIdx.x;
  int gid = blockIdx.x * 1024 + tid;
  int lane = tid & 63, wave = tid >> 6;
  int v = (gid < n) ? cnt[gid] : 0;
  int incl = v;
#pragma unroll
  for (int off = 1; off < 64; off <<= 1) {
    int t = __shfl_up(incl, off);
    if (lane >= off) incl += t;
  }
  if (lane == 63) wsum[wave] = incl;
  __syncthreads();
  if (tid < 16) {
    int s = wsum[tid];
    int is = s;
#pragma unroll
    for (int off = 1; off < 16; off <<= 1) {
      int t = __shfl_up(is, off, 16);
      if (tid >= off) is += t;
    }
    wsum[tid] = is - s;   // exclusive wave offset within block
  }
  __syncthreads();
  if (gid < n) {
    int exc = boff[blockIdx.x] + wsum[wave] + incl - v;
    rowptr[gid] = exc;
    cursor[gid] = exc;
    dis[gid] = rsqrtf((float)v);   // v >= 1 (self-loop)
  }
}

// Fill CSR buckets: 4B src-only entries (norm factorized out: dis[src] is
// folded into t', dis[dst] applied in agg epilogue).
__global__ void k_fill(const int* __restrict__ src, const int* __restrict__ dst,
                       int* __restrict__ cursor, int* __restrict__ csr,
                       int n, int e) {
  int i = blockIdx.x * blockDim.x + threadIdx.x;
  if (i < e) {
    int d = dst[i];
    int pos = atomicAdd(&cursor[d], 1);
    csr[pos] = src[i];
  } else if (i < e + n) {
    int v = i - e;                               // self-loop
    int pos = atomicAdd(&cursor[v], 1);
    csr[pos] = v;
  }
}

// ---------------------------------------------------------------------------
// Tiled fp32 GEMM: C[n x COLS] (+)= A[n x 128] @ B[128 x COLS]
// BF16OUT: epilogue scales row i by dscale[i] (dis), converts to bf16 (RNE).
// ---------------------------------------------------------------------------
template <int COLS, bool ACCUM, bool BF16OUT>
__global__ __launch_bounds__(256) void k_gemm(const float* __restrict__ A,
                                              const float* __restrict__ B,
                                              void* __restrict__ Cv,
                                              const float* __restrict__ dscale,
                                              int n) {
  constexpr int KC = 32;
  constexpr int LDA = 132;
  constexpr int CPT = COLS / 16;
  __shared__ float sA[KC * LDA];
  __shared__ float sB[KC * COLS];
  const int tid = threadIdx.x;
  const int cg = tid & 15;        // 16 col groups
  const int rgb = tid >> 4;       // 16 row groups of 8 rows
  const int row0 = blockIdx.x * 128;

  float acc[8][CPT];
#pragma unroll
  for (int i = 0; i < 8; ++i)
#pragma unroll
    for (int j = 0; j < CPT; ++j) acc[i][j] = 0.f;

  const int skq = tid & 7;        // staging: k-quad
  const int sr = tid >> 3;        // staging: row base (0..31)

  for (int kc = 0; kc < HDIM; kc += KC) {
    __syncthreads();
#pragma unroll
    for (int j = 0; j < 4; ++j) {
      int row = sr + 32 * j;
      int grow = row0 + row;
      float4 v = make_float4(0.f, 0.f, 0.f, 0.f);
      if (grow < n) v = *(const float4*)(A + (size_t)grow * HDIM + kc + skq * 4);
      int kl = skq * 4;
      sA[(kl + 0) * LDA + (row ^ (((kl + 0) & 7) << 2))] = v.x;
      sA[(kl + 1) * LDA + (row ^ (((kl + 1) & 7) << 2))] = v.y;
      sA[(kl + 2) * LDA + (row ^ (((kl + 2) & 7) << 2))] = v.z;
      sA[(kl + 3) * LDA + (row ^ (((kl + 3) & 7) << 2))] = v.w;
    }
    constexpr int NV = KC * COLS / 4;
#pragma unroll
    for (int v4 = tid; v4 < NV; v4 += 256) {
      int k = v4 / (COLS / 4);
      int c4 = (v4 - k * (COLS / 4)) * 4;
      float4 w = *(const float4*)(B + (size_t)(kc + k) * COLS + c4);
      int cp = c4 ^ (((c4 >> 5) & 3) << 2);
      *(float4*)(&sB[k * COLS + cp]) = w;
    }
    __syncthreads();
#pragma unroll 4
    for (int k = 0; k < KC; ++k) {
      int msk = (k & 7) << 2;
      float a[8];
      {
        float4 a0 = *(const float4*)(&sA[k * LDA + ((rgb * 8) ^ msk)]);
        float4 a1 = *(const float4*)(&sA[k * LDA + ((rgb * 8 + 4) ^ msk)]);
        a[0] = a0.x; a[1] = a0.y; a[2] = a0.z; a[3] = a0.w;
        a[4] = a1.x; a[5] = a1.y; a[6] = a1.z; a[7] = a1.w;
      }
      float b[CPT];
#pragma unroll
      for (int s = 0; s < CPT / 4; ++s) {
        int c0 = cg * CPT + s * 4;
        int cp = c0 ^ (((c0 >> 5) & 3) << 2);
        float4 w = *(const float4*)(&sB[k * COLS + cp]);
        b[s * 4 + 0] = w.x; b[s * 4 + 1] = w.y;
        b[s * 4 + 2] = w.z; b[s * 4 + 3] = w.w;
      }
#pragma unroll
      for (int i = 0; i < 8; ++i)
#pragma unroll
        for (int j = 0; j < CPT; ++j) acc[i][j] = fmaf(a[i], b[j], acc[i][j]);
    }
  }
  // epilogue
#pragma unroll
  for (int i = 0; i < 8; ++i) {
    int grow = row0 + rgb * 8 + i;
    if (grow < n) {
      float ds = BF16OUT ? dscale[grow] : 1.f;
#pragma unroll
      for (int s = 0; s < CPT / 4; ++s) {
        float4 o;
        o.x = acc[i][s * 4 + 0]; o.y = acc[i][s * 4 + 1];
        o.z = acc[i][s * 4 + 2]; o.w = acc[i][s * 4 + 3];
        if (BF16OUT) {
          o.x *= ds; o.y *= ds; o.z *= ds; o.w *= ds;
          ushort16* Cb = (ushort16*)Cv;
          uint32 lo = (uint32)f2bf_rne(o.x) | ((uint32)f2bf_rne(o.y) << 16);
          uint32 hi = (uint32)f2bf_rne(o.z) | ((uint32)f2bf_rne(o.w) << 16);
          uint2 pk; pk.x = lo; pk.y = hi;
          *(uint2*)(Cb + (size_t)grow * COLS + cg * CPT + s * 4) = pk;
        } else {
          float* C = (float*)Cv;
          float* cp = C + (size_t)grow * COLS + cg * CPT + s * 4;
          if (ACCUM) {
            float4 prev = *(const float4*)cp;
            o.x += prev.x; o.y += prev.y; o.z += prev.z; o.w += prev.w;
          }
          *(float4*)cp = o;
        }
      }
    }
  }
}

// ---------------------------------------------------------------------------
// CSR-gather aggregation over bf16 t' (= t * dis[src]). One wave per node;
// each QUARTER-wave (16 lanes x 16B = one full 256B bf16 row) owns one edge
// -> 4 edges per wave-instruction, 8 rows in flight in the main loop.
// Lane covers 8 features; quarters folded with shfl_xor(32), shfl_xor(16).
// hout[v] = relu( dis[v] * sum_{u in CSR[v]} t'[u] + bias )   (fp32 out)
// ---------------------------------------------------------------------------
__global__ __launch_bounds__(256) void k_agg(const ushort16* __restrict__ tb,
                                             const int* __restrict__ rowptr,
                                             const int* __restrict__ csr,
                                             const float* __restrict__ dis,
                                             const float* __restrict__ bias,
                                             float* __restrict__ hout, int n) {
  const int lane = threadIdx.x & 63;
  const int q = lane >> 4;             // quarter id: which edge of the 4
  const int fl = (lane & 15) * 8;      // feature base (8 bf16 = 16B per lane)
  const float4 bv0 = *(const float4*)(bias + fl);
  const float4 bv1 = *(const float4*)(bias + fl + 4);
  const int wid = blockIdx.x * 4 + (threadIdx.x >> 6);
  const int nw = gridDim.x * 4;
  for (int v = wid; v < n; v += nw) {
    const int e0 = rowptr[v];
    const int e1 = rowptr[v + 1];
    float a0 = 0.f, a1 = 0.f, a2 = 0.f, a3 = 0.f;
    float a4 = 0.f, a5 = 0.f, a6 = 0.f, a7 = 0.f;
    int e = e0;
    for (; e + 7 < e1; e += 8) {       // 8 edges/iter (2 per quarter)
      int uA = csr[e + q];
      int uB = csr[e + 4 + q];
      uint4 ta = *(const uint4*)(tb + ((size_t)uA << 7) + fl);
      uint4 tc = *(const uint4*)(tb + ((size_t)uB << 7) + fl);
      a0 += bf_lo(ta.x); a1 += bf_hi(ta.x);
      a2 += bf_lo(ta.y); a3 += bf_hi(ta.y);
      a4 += bf_lo(ta.z); a5 += bf_hi(ta.z);
      a6 += bf_lo(ta.w); a7 += bf_hi(ta.w);
      a0 += bf_lo(tc.x); a1 += bf_hi(tc.x);
      a2 += bf_lo(tc.y); a3 += bf_hi(tc.y);
      a4 += bf_lo(tc.z); a5 += bf_hi(tc.z);
      a6 += bf_lo(tc.w); a7 += bf_hi(tc.w);
    }
    for (; e < e1; e += 4) {           // masked tail (1-7 leftovers)
      int idx = e + q;
      if (idx < e1) {
        int u = csr[idx];
        uint4 ta = *(const uint4*)(tb + ((size_t)u << 7) + fl);
        a0 += bf_lo(ta.x); a1 += bf_hi(ta.x);
        a2 += bf_lo(ta.y); a3 += bf_hi(ta.y);
        a4 += bf_lo(ta.z); a5 += bf_hi(ta.z);
        a6 += bf_lo(ta.w); a7 += bf_hi(ta.w);
      }
    }
    // fold the four quarter-wave partial sums
    a0 += __shfl_xor(a0, 32); a1 += __shfl_xor(a1, 32);
    a2 += __shfl_xor(a2, 32); a3 += __shfl_xor(a3, 32);
    a4 += __shfl_xor(a4, 32); a5 += __shfl_xor(a5, 32);
    a6 += __shfl_xor(a6, 32); a7 += __shfl_xor(a7, 32);
    a0 += __shfl_xor(a0, 16); a1 += __shfl_xor(a1, 16);
    a2 += __shfl_xor(a2, 16); a3 += __shfl_xor(a3, 16);
    a4 += __shfl_xor(a4, 16); a5 += __shfl_xor(a5, 16);
    a6 += __shfl_xor(a6, 16); a7 += __shfl_xor(a7, 16);
    if (q == 0) {
      const float dv = dis[v];
      float4 h0, h1;
      h0.x = fmaxf(fmaf(a0, dv, bv0.x), 0.f);
      h0.y = fmaxf(fmaf(a1, dv, bv0.y), 0.f);
      h0.z = fmaxf(fmaf(a2, dv, bv0.z), 0.f);
      h0.w = fmaxf(fmaf(a3, dv, bv0.w), 0.f);
      h1.x = fmaxf(fmaf(a4, dv, bv1.x), 0.f);
      h1.y = fmaxf(fmaf(a5, dv, bv1.y), 0.f);
      h1.z = fmaxf(fmaf(a6, dv, bv1.z), 0.f);
      h1.w = fmaxf(fmaf(a7, dv, bv1.w), 0.f);
      float* hp = hout + (size_t)v * HDIM + fl;
      *(float4*)hp = h0;
      *(float4*)(hp + 4) = h1;
    }
  }
}

// ---------------------------------------------------------------------------
extern "C" void kernel_launch(void* const* d_in, const int* in_sizes, int n_in,
                              void* d_out, int out_size, void* d_ws, size_t ws_size,
                              hipStream_t stream) {
  (void)n_in; (void)out_size; (void)ws_size;
  const float* x  = (const float*)d_in[0];
  const int*   ei = (const int*)d_in[1];
  const float* Ws = (const float*)d_in[2];
  const float* bs = (const float*)d_in[3];
  const float* lw = (const float*)d_in[4];
  const float* lb = (const float*)d_in[5];
  float* out = (float*)d_out;

  const int n = in_sizes[0] / HDIM;
  const int e = in_sizes[1] / 2;
  const int* src = ei;
  const int* dst = ei + e;
  const int nb = (n + 1023) / 1024;   // scan level-1 block count

  // workspace carve-out
  char* p = (char*)d_ws;
  auto take = [&](size_t bytes) {
    char* r = p;
    p += (bytes + 255) & ~(size_t)255;
    return (void*)r;
  };
  int*      cnt    = (int*)take((size_t)n * 4);
  int*      rowptr = (int*)take((size_t)(n + 1) * 4);
  int*      cursor = (int*)take((size_t)n * 4);
  float*    dis    = (float*)take((size_t)n * 4);
  int*      bsum   = (int*)take((size_t)nb * 4);
  int*      boff   = (int*)take((size_t)nb * 4);
  int*      csr    = (int*)take((size_t)(e + n) * 4);        // 4B src-only
  ushort16* tbuf   = (ushort16*)take((size_t)n * HDIM * 2);  // bf16 t'
  float*    hbuf   = (float*)take((size_t)n * HDIM * 4);

  // CSR build (once; reused by all 3 layers)
  k_prep<<<1024, 256, 0, stream>>>(cnt, out, lb, n);
  k_count<<<(e + 255) / 256, 256, 0, stream>>>(dst, cnt, e);
  k_scan1<<<nb, 1024, 0, stream>>>(cnt, bsum, n);
  k_scan2<<<1, 64, 0, stream>>>(bsum, boff, rowptr, nb, n);
  k_scan3<<<nb, 1024, 0, stream>>>(cnt, boff, rowptr, cursor, dis, n);
  k_fill<<<(e + n + 255) / 256, 256, 0, stream>>>(src, dst, cursor, csr, n, e);

  // 3 GCN layers; output projection fused per layer (out pre-seeded with lin_b)
  const int gtiles = (n + 127) / 128;
  const float* hin = x;
  for (int l = 0; l < NLAYERS; ++l) {
    k_gemm<HDIM, false, true><<<gtiles, 256, 0, stream>>>(
        hin, Ws + (size_t)l * HDIM * HDIM, tbuf, dis, n);
    k_agg<<<2048, 256, 0, stream>>>(
        tbuf, rowptr, csr, dis, bs + (size_t)l * HDIM, hbuf, n);
    k_gemm<RDIM, true, false><<<gtiles, 256, 0, stream>>>(
        hbuf, lw + (size_t)l * HDIM * RDIM, out, nullptr, n);
    hin = hbuf;
  }
}

// Round 7
// 704.074 us; speedup vs baseline: 1.0275x; 1.0275x over previous
//
#include <hip/hip_runtime.h>

#define HDIM 128
#define RDIM 64
#define NLAYERS 3

typedef unsigned int uint32;
typedef unsigned short ushort16;

// round-to-nearest-even fp32 -> bf16 (as raw ushort)
__device__ __forceinline__ ushort16 f2bf_rne(float x) {
  uint32 u = __float_as_uint(x);
  u += 0x7FFFu + ((u >> 16) & 1u);
  return (ushort16)(u >> 16);
}
__device__ __forceinline__ float bf_lo(uint32 p) { return __uint_as_float(p << 16); }
__device__ __forceinline__ float bf_hi(uint32 p) { return __uint_as_float(p & 0xFFFF0000u); }

// ---------------------------------------------------------------------------
// Phase 0: init degree counts (self-loop => 1) and out (= lin_b broadcast)
// ---------------------------------------------------------------------------
__global__ void k_prep(int* __restrict__ cnt, float* __restrict__ out,
                       const float* __restrict__ lin_b, int n) {
  int stride = gridDim.x * blockDim.x;
  int i0 = blockIdx.x * blockDim.x + threadIdx.x;
  for (int i = i0; i < n; i += stride) cnt[i] = 1;
  int total = n * RDIM;
  for (int i = i0; i < total; i += stride) out[i] = lin_b[i & (RDIM - 1)];
}

// 4 edges/thread, int4 loads (no-return atomics have no dependent chain).
__global__ void k_count(const int* __restrict__ dst, int* __restrict__ cnt, int e) {
  int i0 = (blockIdx.x * blockDim.x + threadIdx.x) * 4;
  if (i0 + 3 < e) {
    int4 d4 = *(const int4*)(dst + i0);
    atomicAdd(&cnt[d4.x], 1);
    atomicAdd(&cnt[d4.y], 1);
    atomicAdd(&cnt[d4.z], 1);
    atomicAdd(&cnt[d4.w], 1);
  } else {
    for (int i = i0; i < e; ++i) atomicAdd(&cnt[dst[i]], 1);
  }
}

// ---------------------------------------------------------------------------
// Two-level parallel exclusive scan over cnt[] -> rowptr/cursor (+ dis fused).
// ---------------------------------------------------------------------------
__global__ __launch_bounds__(1024) void k_scan1(const int* __restrict__ cnt,
                                                int* __restrict__ bsum, int n) {
  __shared__ int red[16];
  int tid = threadIdx.x;
  int gid = blockIdx.x * 1024 + tid;
  int v = (gid < n) ? cnt[gid] : 0;
#pragma unroll
  for (int off = 1; off < 64; off <<= 1) v += __shfl_xor(v, off);
  if ((tid & 63) == 0) red[tid >> 6] = v;
  __syncthreads();
  if (tid < 16) {
    int s = red[tid];
#pragma unroll
    for (int off = 1; off < 16; off <<= 1) s += __shfl_xor(s, off, 16);
    if (tid == 0) bsum[blockIdx.x] = s;
  }
}

__global__ __launch_bounds__(64) void k_scan2(const int* __restrict__ bsum,
                                              int* __restrict__ boff,
                                              int* __restrict__ rowptr,
                                              int nb, int n) {
  int lane = threadIdx.x;
  int carry = 0;
  for (int base = 0; base < nb; base += 64) {
    int i = base + lane;
    int v = (i < nb) ? bsum[i] : 0;
    int incl = v;
#pragma unroll
    for (int off = 1; off < 64; off <<= 1) {
      int t = __shfl_up(incl, off);
      if (lane >= off) incl += t;
    }
    if (i < nb) boff[i] = carry + incl - v;
    carry += __shfl(incl, 63);
  }
  if (lane == 0) rowptr[n] = carry;
}

// Level 3: rowptr/cursor/dis; self-loop pre-placed at slot 0 of each bucket
// (csr[rowptr[v]] = v, cursor starts at rowptr[v]+1) — removes n atomics and
// n random stores from k_fill.
__global__ __launch_bounds__(1024) void k_scan3(const int* __restrict__ cnt,
                                                const int* __restrict__ boff,
                                                int* __restrict__ rowptr,
                                                int* __restrict__ cursor,
                                                float* __restrict__ dis,
                                                int* __restrict__ csr, int n) {
  __shared__ int wsum[16];
  int tid = threadIdx.x;
  int gid = blockIdx.x * 1024 + tid;
  int lane = tid & 63, wave = tid >> 6;
  int v = (gid < n) ? cnt[gid] : 0;
  int incl = v;
#pragma unroll
  for (int off = 1; off < 64; off <<= 1) {
    int t = __shfl_up(incl, off);
    if (lane >= off) incl += t;
  }
  if (lane == 63) wsum[wave] = incl;
  __syncthreads();
  if (tid < 16) {
    int s = wsum[tid];
    int is = s;
#pragma unroll
    for (int off = 1; off < 16; off <<= 1) {
      int t = __shfl_up(is, off, 16);
      if (tid >= off) is += t;
    }
    wsum[tid] = is - s;   // exclusive wave offset within block
  }
  __syncthreads();
  if (gid < n) {
    int exc = boff[blockIdx.x] + wsum[wave] + incl - v;
    rowptr[gid] = exc;
    cursor[gid] = exc + 1;       // slot 0 taken by self-loop
    csr[exc] = gid;              // self-loop entry
    dis[gid] = rsqrtf((float)v); // v >= 1 (self-loop)
  }
}

// Fill CSR buckets: 8 edges/thread for deep MLP (8 independent atomic->store
// chains in flight; round-6 lesson: 1 chain/thread at 4 VGPRs serializes).
__global__ void k_fill(const int* __restrict__ src, const int* __restrict__ dst,
                       int* __restrict__ cursor, int* __restrict__ csr, int e) {
  int i0 = (blockIdx.x * blockDim.x + threadIdx.x) * 8;
  if (i0 + 7 < e) {
    int4 sa = *(const int4*)(src + i0);
    int4 sb = *(const int4*)(src + i0 + 4);
    int4 da = *(const int4*)(dst + i0);
    int4 db = *(const int4*)(dst + i0 + 4);
    int p0 = atomicAdd(&cursor[da.x], 1);
    int p1 = atomicAdd(&cursor[da.y], 1);
    int p2 = atomicAdd(&cursor[da.z], 1);
    int p3 = atomicAdd(&cursor[da.w], 1);
    int p4 = atomicAdd(&cursor[db.x], 1);
    int p5 = atomicAdd(&cursor[db.y], 1);
    int p6 = atomicAdd(&cursor[db.z], 1);
    int p7 = atomicAdd(&cursor[db.w], 1);
    csr[p0] = sa.x; csr[p1] = sa.y; csr[p2] = sa.z; csr[p3] = sa.w;
    csr[p4] = sb.x; csr[p5] = sb.y; csr[p6] = sb.z; csr[p7] = sb.w;
  } else {
    for (int i = i0; i < e; ++i) {
      int pos = atomicAdd(&cursor[dst[i]], 1);
      csr[pos] = src[i];
    }
  }
}

// ---------------------------------------------------------------------------
// Tiled fp32 GEMM: C[n x COLS] (+)= A[n x 128] @ B[128 x COLS]
// BF16OUT: epilogue scales row i by dscale[i] (dis), converts to bf16 (RNE).
// ---------------------------------------------------------------------------
template <int COLS, bool ACCUM, bool BF16OUT>
__global__ __launch_bounds__(256) void k_gemm(const float* __restrict__ A,
                                              const float* __restrict__ B,
                                              void* __restrict__ Cv,
                                              const float* __restrict__ dscale,
                                              int n) {
  constexpr int KC = 32;
  constexpr int LDA = 132;
  constexpr int CPT = COLS / 16;
  __shared__ float sA[KC * LDA];
  __shared__ float sB[KC * COLS];
  const int tid = threadIdx.x;
  const int cg = tid & 15;        // 16 col groups
  const int rgb = tid >> 4;       // 16 row groups of 8 rows
  const int row0 = blockIdx.x * 128;

  float acc[8][CPT];
#pragma unroll
  for (int i = 0; i < 8; ++i)
#pragma unroll
    for (int j = 0; j < CPT; ++j) acc[i][j] = 0.f;

  const int skq = tid & 7;        // staging: k-quad
  const int sr = tid >> 3;        // staging: row base (0..31)

  for (int kc = 0; kc < HDIM; kc += KC) {
    __syncthreads();
#pragma unroll
    for (int j = 0; j < 4; ++j) {
      int row = sr + 32 * j;
      int grow = row0 + row;
      float4 v = make_float4(0.f, 0.f, 0.f, 0.f);
      if (grow < n) v = *(const float4*)(A + (size_t)grow * HDIM + kc + skq * 4);
      int kl = skq * 4;
      sA[(kl + 0) * LDA + (row ^ (((kl + 0) & 7) << 2))] = v.x;
      sA[(kl + 1) * LDA + (row ^ (((kl + 1) & 7) << 2))] = v.y;
      sA[(kl + 2) * LDA + (row ^ (((kl + 2) & 7) << 2))] = v.z;
      sA[(kl + 3) * LDA + (row ^ (((kl + 3) & 7) << 2))] = v.w;
    }
    constexpr int NV = KC * COLS / 4;
#pragma unroll
    for (int v4 = tid; v4 < NV; v4 += 256) {
      int k = v4 / (COLS / 4);
      int c4 = (v4 - k * (COLS / 4)) * 4;
      float4 w = *(const float4*)(B + (size_t)(kc + k) * COLS + c4);
      int cp = c4 ^ (((c4 >> 5) & 3) << 2);
      *(float4*)(&sB[k * COLS + cp]) = w;
    }
    __syncthreads();
#pragma unroll 4
    for (int k = 0; k < KC; ++k) {
      int msk = (k & 7) << 2;
      float a[8];
      {
        float4 a0 = *(const float4*)(&sA[k * LDA + ((rgb * 8) ^ msk)]);
        float4 a1 = *(const float4*)(&sA[k * LDA + ((rgb * 8 + 4) ^ msk)]);
        a[0] = a0.x; a[1] = a0.y; a[2] = a0.z; a[3] = a0.w;
        a[4] = a1.x; a[5] = a1.y; a[6] = a1.z; a[7] = a1.w;
      }
      float b[CPT];
#pragma unroll
      for (int s = 0; s < CPT / 4; ++s) {
        int c0 = cg * CPT + s * 4;
        int cp = c0 ^ (((c0 >> 5) & 3) << 2);
        float4 w = *(const float4*)(&sB[k * COLS + cp]);
        b[s * 4 + 0] = w.x; b[s * 4 + 1] = w.y;
        b[s * 4 + 2] = w.z; b[s * 4 + 3] = w.w;
      }
#pragma unroll
      for (int i = 0; i < 8; ++i)
#pragma unroll
        for (int j = 0; j < CPT; ++j) acc[i][j] = fmaf(a[i], b[j], acc[i][j]);
    }
  }
  // epilogue
#pragma unroll
  for (int i = 0; i < 8; ++i) {
    int grow = row0 + rgb * 8 + i;
    if (grow < n) {
      float ds = BF16OUT ? dscale[grow] : 1.f;
#pragma unroll
      for (int s = 0; s < CPT / 4; ++s) {
        float4 o;
        o.x = acc[i][s * 4 + 0]; o.y = acc[i][s * 4 + 1];
        o.z = acc[i][s * 4 + 2]; o.w = acc[i][s * 4 + 3];
        if (BF16OUT) {
          o.x *= ds; o.y *= ds; o.z *= ds; o.w *= ds;
          ushort16* Cb = (ushort16*)Cv;
          uint32 lo = (uint32)f2bf_rne(o.x) | ((uint32)f2bf_rne(o.y) << 16);
          uint32 hi = (uint32)f2bf_rne(o.z) | ((uint32)f2bf_rne(o.w) << 16);
          uint2 pk; pk.x = lo; pk.y = hi;
          *(uint2*)(Cb + (size_t)grow * COLS + cg * CPT + s * 4) = pk;
        } else {
          float* C = (float*)Cv;
          float* cp = C + (size_t)grow * COLS + cg * CPT + s * 4;
          if (ACCUM) {
            float4 prev = *(const float4*)cp;
            o.x += prev.x; o.y += prev.y; o.z += prev.z; o.w += prev.w;
          }
          *(float4*)cp = o;
        }
      }
    }
  }
}

// ---------------------------------------------------------------------------
// CSR-gather aggregation over bf16 t' (= t * dis[src]). One wave per node;
// each QUARTER-wave (16 lanes x 16B = one full 256B bf16 row) owns one edge
// -> 4 edges per wave-instruction, 8 rows in flight in the main loop.
// hout[v] = relu( dis[v] * sum_{u in CSR[v]} t'[u] + bias )   (fp32 out)
// ---------------------------------------------------------------------------
__global__ __launch_bounds__(256) void k_agg(const ushort16* __restrict__ tb,
                                             const int* __restrict__ rowptr,
                                             const int* __restrict__ csr,
                                             const float* __restrict__ dis,
                                             const float* __restrict__ bias,
                                             float* __restrict__ hout, int n) {
  const int lane = threadIdx.x & 63;
  const int q = lane >> 4;             // quarter id: which edge of the 4
  const int fl = (lane & 15) * 8;      // feature base (8 bf16 = 16B per lane)
  const float4 bv0 = *(const float4*)(bias + fl);
  const float4 bv1 = *(const float4*)(bias + fl + 4);
  const int wid = blockIdx.x * 4 + (threadIdx.x >> 6);
  const int nw = gridDim.x * 4;
  for (int v = wid; v < n; v += nw) {
    const int e0 = rowptr[v];
    const int e1 = rowptr[v + 1];
    float a0 = 0.f, a1 = 0.f, a2 = 0.f, a3 = 0.f;
    float a4 = 0.f, a5 = 0.f, a6 = 0.f, a7 = 0.f;
    int e = e0;
    for (; e + 7 < e1; e += 8) {       // 8 edges/iter (2 per quarter)
      int uA = csr[e + q];
      int uB = csr[e + 4 + q];
      uint4 ta = *(const uint4*)(tb + ((size_t)uA << 7) + fl);
      uint4 tc = *(const uint4*)(tb + ((size_t)uB << 7) + fl);
      a0 += bf_lo(ta.x); a1 += bf_hi(ta.x);
      a2 += bf_lo(ta.y); a3 += bf_hi(ta.y);
      a4 += bf_lo(ta.z); a5 += bf_hi(ta.z);
      a6 += bf_lo(ta.w); a7 += bf_hi(ta.w);
      a0 += bf_lo(tc.x); a1 += bf_hi(tc.x);
      a2 += bf_lo(tc.y); a3 += bf_hi(tc.y);
      a4 += bf_lo(tc.z); a5 += bf_hi(tc.z);
      a6 += bf_lo(tc.w); a7 += bf_hi(tc.w);
    }
    for (; e < e1; e += 4) {           // masked tail (1-7 leftovers)
      int idx = e + q;
      if (idx < e1) {
        int u = csr[idx];
        uint4 ta = *(const uint4*)(tb + ((size_t)u << 7) + fl);
        a0 += bf_lo(ta.x); a1 += bf_hi(ta.x);
        a2 += bf_lo(ta.y); a3 += bf_hi(ta.y);
        a4 += bf_lo(ta.z); a5 += bf_hi(ta.z);
        a6 += bf_lo(ta.w); a7 += bf_hi(ta.w);
      }
    }
    // fold the four quarter-wave partial sums
    a0 += __shfl_xor(a0, 32); a1 += __shfl_xor(a1, 32);
    a2 += __shfl_xor(a2, 32); a3 += __shfl_xor(a3, 32);
    a4 += __shfl_xor(a4, 32); a5 += __shfl_xor(a5, 32);
    a6 += __shfl_xor(a6, 32); a7 += __shfl_xor(a7, 32);
    a0 += __shfl_xor(a0, 16); a1 += __shfl_xor(a1, 16);
    a2 += __shfl_xor(a2, 16); a3 += __shfl_xor(a3, 16);
    a4 += __shfl_xor(a4, 16); a5 += __shfl_xor(a5, 16);
    a6 += __shfl_xor(a6, 16); a7 += __shfl_xor(a7, 16);
    if (q == 0) {
      const float dv = dis[v];
      float4 h0, h1;
      h0.x = fmaxf(fmaf(a0, dv, bv0.x), 0.f);
      h0.y = fmaxf(fmaf(a1, dv, bv0.y), 0.f);
      h0.z = fmaxf(fmaf(a2, dv, bv0.z), 0.f);
      h0.w = fmaxf(fmaf(a3, dv, bv0.w), 0.f);
      h1.x = fmaxf(fmaf(a4, dv, bv1.x), 0.f);
      h1.y = fmaxf(fmaf(a5, dv, bv1.y), 0.f);
      h1.z = fmaxf(fmaf(a6, dv, bv1.z), 0.f);
      h1.w = fmaxf(fmaf(a7, dv, bv1.w), 0.f);
      float* hp = hout + (size_t)v * HDIM + fl;
      *(float4*)hp = h0;
      *(float4*)(hp + 4) = h1;
    }
  }
}

// ---------------------------------------------------------------------------
extern "C" void kernel_launch(void* const* d_in, const int* in_sizes, int n_in,
                              void* d_out, int out_size, void* d_ws, size_t ws_size,
                              hipStream_t stream) {
  (void)n_in; (void)out_size; (void)ws_size;
  const float* x  = (const float*)d_in[0];
  const int*   ei = (const int*)d_in[1];
  const float* Ws = (const float*)d_in[2];
  const float* bs = (const float*)d_in[3];
  const float* lw = (const float*)d_in[4];
  const float* lb = (const float*)d_in[5];
  float* out = (float*)d_out;

  const int n = in_sizes[0] / HDIM;
  const int e = in_sizes[1] / 2;
  const int* src = ei;
  const int* dst = ei + e;
  const int nb = (n + 1023) / 1024;   // scan level-1 block count

  // workspace carve-out
  char* p = (char*)d_ws;
  auto take = [&](size_t bytes) {
    char* r = p;
    p += (bytes + 255) & ~(size_t)255;
    return (void*)r;
  };
  int*      cnt    = (int*)take((size_t)n * 4);
  int*      rowptr = (int*)take((size_t)(n + 1) * 4);
  int*      cursor = (int*)take((size_t)n * 4);
  float*    dis    = (float*)take((size_t)n * 4);
  int*      bsum   = (int*)take((size_t)nb * 4);
  int*      boff   = (int*)take((size_t)nb * 4);
  int*      csr    = (int*)take((size_t)(e + n) * 4);        // 4B src-only
  ushort16* tbuf   = (ushort16*)take((size_t)n * HDIM * 2);  // bf16 t'
  float*    hbuf   = (float*)take((size_t)n * HDIM * 4);

  // CSR build (once; reused by all 3 layers)
  k_prep<<<1024, 256, 0, stream>>>(cnt, out, lb, n);
  k_count<<<(e / 4 + 255) / 256, 256, 0, stream>>>(dst, cnt, e);
  k_scan1<<<nb, 1024, 0, stream>>>(cnt, bsum, n);
  k_scan2<<<1, 64, 0, stream>>>(bsum, boff, rowptr, nb, n);
  k_scan3<<<nb, 1024, 0, stream>>>(cnt, boff, rowptr, cursor, dis, csr, n);
  k_fill<<<(e / 8 + 255) / 256, 256, 0, stream>>>(src, dst, cursor, csr, e);

  // 3 GCN layers; output projection fused per layer (out pre-seeded with lin_b)
  const int gtiles = (n + 127) / 128;
  const float* hin = x;
  for (int l = 0; l < NLAYERS; ++l) {
    k_gemm<HDIM, false, true><<<gtiles, 256, 0, stream>>>(
        hin, Ws + (size_t)l * HDIM * HDIM, tbuf, dis, n);
    k_agg<<<2048, 256, 0, stream>>>(
        tbuf, rowptr, csr, dis, bs + (size_t)l * HDIM, hbuf, n);
    k_gemm<RDIM, true, false><<<gtiles, 256, 0, stream>>>(
        hbuf, lw + (size_t)l * HDIM * RDIM, out, nullptr, n);
    hin = hbuf;
  }
}